// Round 2
// baseline (1801.732 us; speedup 1.0000x reference)
//
#include <hip/hip_runtime.h>

typedef unsigned short u16;
typedef _Float16 f16x8 __attribute__((ext_vector_type(8)));
typedef float f32x4 __attribute__((ext_vector_type(4)));

#define AS1 __attribute__((address_space(1)))
#define AS3 __attribute__((address_space(3)))

constexpr int N_NODES = 8000;
constexpr int N_EDGES = 64000;
constexpr int F_IN    = 2560;   // in channels (== H*C, both layers)
constexpr int HEADS   = 8;
constexpr int CPH     = 320;    // channels per head
constexpr int HC      = 2560;   // HEADS*CPH
constexpr int NGRAPH  = 16;
constexpr float SLOPE = 0.2f;

// ---------------- f32 -> f16 bulk convert (n divisible by 1024) ----------------
__global__ __launch_bounds__(256)
void cvt_f32_f16(const float* __restrict__ in, u16* __restrict__ out, int n)
{
  const int i = (blockIdx.x * 256 + threadIdx.x) * 4;
  if (i >= n) return;
  const float4 v = *(const float4*)(in + i);
  _Float16 h0 = (_Float16)v.x, h1 = (_Float16)v.y, h2 = (_Float16)v.z, h3 = (_Float16)v.w;
  u16 o[4];
  __builtin_memcpy(&o[0], &h0, 2); __builtin_memcpy(&o[1], &h1, 2);
  __builtin_memcpy(&o[2], &h2, 2); __builtin_memcpy(&o[3], &h3, 2);
  *(ushort4*)(out + i) = *(const ushort4*)o;
}

// ------------- weight transpose + convert: in f32 [R=2560][C=2560] -> out f16 [C][R] -------------
__global__ __launch_bounds__(256)
void transpose_w(const float* __restrict__ in, u16* __restrict__ out)
{
  __shared__ u16 tile[64][66];     // +2 pad to break bank stride
  const int bx = blockIdx.x * 64;  // col tile (input)
  const int by = blockIdx.y * 64;  // row tile (input)
  const int tx = threadIdx.x & 63;
  const int ty = threadIdx.x >> 6;
  #pragma unroll
  for (int i = ty; i < 64; i += 4) {
    _Float16 h = (_Float16)in[(size_t)(by + i) * HC + bx + tx];
    u16 u; __builtin_memcpy(&u, &h, 2);
    tile[i][tx] = u;
  }
  __syncthreads();
  #pragma unroll
  for (int i = ty; i < 64; i += 4)
    out[(size_t)(bx + i) * F_IN + by + tx] = tile[tx][i];
}

// ---- GEMM: C[M,N](f32) = A[M,K](f16) @ BT[N,K](f16)^T + bias(f32); fp32 accum ----
// m97 structure: 128x128 tile, BK=32, 4 waves (2x2), 16x16x32 f16 MFMA.
__global__ __launch_bounds__(256)
void gemm_bias(const u16* __restrict__ A, const u16* __restrict__ BT,
               const float* __restrict__ bias, float* __restrict__ C,
               int M, int Nout, int K)
{
  __shared__ __align__(16) u16 sA[128 * 32];
  __shared__ __align__(16) u16 sB[128 * 32];
  const int t    = threadIdx.x;
  const int lane = t & 63;
  const int wave = t >> 6;
  const int m0 = blockIdx.x * 128;
  const int n0 = blockIdx.y * 128;
  const int fm = (wave >> 1) * 64;
  const int fn = (wave & 1) * 64;
  const int ml = lane & 15;
  const int kl = (lane >> 4) * 8;

  f32x4 acc[4][4] = {};

  for (int k0 = 0; k0 < K; k0 += 32) {
    __syncthreads();
    #pragma unroll
    for (int jj = 0; jj < 2; ++jj) {
      const int flat = jj * 256 + t;
      const int r  = flat >> 2;
      const int kc = (flat & 3) << 3;
      int ra = m0 + r; ra = (ra < M) ? ra : (M - 1);
      const u16* ga = A + (size_t)ra * K + k0 + kc;
      __builtin_amdgcn_global_load_lds((AS1 const void*)ga,
                                       (AS3 void*)(sA + flat * 8), 16, 0, 0);
      int rb = n0 + r; rb = (rb < Nout) ? rb : (Nout - 1);
      const u16* gb = BT + (size_t)rb * K + k0 + kc;
      __builtin_amdgcn_global_load_lds((AS1 const void*)gb,
                                       (AS3 void*)(sB + flat * 8), 16, 0, 0);
    }
    __syncthreads();

    f16x8 af[4], bfr[4];
    #pragma unroll
    for (int i = 0; i < 4; ++i)
      af[i] = *(const f16x8*)(sA + (fm + i * 16 + ml) * 32 + kl);
    #pragma unroll
    for (int j = 0; j < 4; ++j)
      bfr[j] = *(const f16x8*)(sB + (fn + j * 16 + ml) * 32 + kl);

    #pragma unroll
    for (int i = 0; i < 4; ++i)
      #pragma unroll
      for (int j = 0; j < 4; ++j)
        acc[i][j] = __builtin_amdgcn_mfma_f32_16x16x32_f16(af[i], bfr[j], acc[i][j], 0, 0, 0);
  }

  const int rg = (lane >> 4) * 4;
  #pragma unroll
  for (int j = 0; j < 4; ++j) {
    const int gn = n0 + fn + j * 16 + ml;
    const float bv = bias[gn];
    #pragma unroll
    for (int i = 0; i < 4; ++i) {
      #pragma unroll
      for (int r = 0; r < 4; ++r) {
        const int gm = m0 + fm + i * 16 + rg + r;
        if (gm < M) C[(size_t)gm * Nout + gn] = acc[i][j][r] + bv;
      }
    }
  }
}

// ---------------- CSR build ----------------
__global__ __launch_bounds__(256)
void count_edges(const int* __restrict__ dst, int* __restrict__ counts)
{
  const int e = blockIdx.x * 256 + threadIdx.x;
  if (e < N_EDGES) atomicAdd(&counts[dst[e]], 1);
}

__global__ __launch_bounds__(256)
void scan_offsets(const int* __restrict__ counts, int* __restrict__ offs, int* __restrict__ cur)
{
  __shared__ int wtot[4];
  const int t = threadIdx.x;
  const int lane = t & 63, wave = t >> 6;
  const int base = t * 32;
  int loc[32];
  int run = 0;
  #pragma unroll
  for (int i = 0; i < 32; ++i) {
    const int idx = base + i;
    const int v = (idx < N_NODES) ? counts[idx] : 0;
    loc[i] = run;
    run += v;
  }
  int incl = run;
  #pragma unroll
  for (int off = 1; off < 64; off <<= 1) {
    int y = __shfl_up(incl, off, 64);
    if (lane >= off) incl += y;
  }
  const int excl = incl - run;
  if (lane == 63) wtot[wave] = incl;
  __syncthreads();
  int wb = 0;
  for (int wv = 0; wv < wave; ++wv) wb += wtot[wv];
  const int mybase = wb + excl;
  #pragma unroll
  for (int i = 0; i < 32; ++i) {
    const int idx = base + i;
    if (idx < N_NODES) { offs[idx] = mybase + loc[i]; cur[idx] = mybase + loc[i]; }
  }
  if (t == 255) offs[N_NODES] = wb + incl;
}

__global__ __launch_bounds__(256)
void fill_csr(const int* __restrict__ dst, int* __restrict__ cur, int* __restrict__ eids)
{
  const int e = blockIdx.x * 256 + threadIdx.x;
  if (e < N_EDGES) {
    const int p = atomicAdd(&cur[dst[e]], 1);
    eids[p] = e;
  }
}

// ---------------- edge scores: one wave per (edge, head), all f32 ----------------
__global__ __launch_bounds__(256)
void edge_scores(const float* __restrict__ XL, const float* __restrict__ XR,
                 const float* __restrict__ We, const float* __restrict__ att,
                 const float* __restrict__ eattr,
                 const int* __restrict__ src, const int* __restrict__ dst,
                 float* __restrict__ score)
{
  const int W = (blockIdx.x * 256 + threadIdx.x) >> 6;
  const int lane = threadIdx.x & 63;
  if (W >= N_EDGES * HEADS) return;
  const int e = W >> 3, h = W & 7;
  const int s = src[e], d = dst[e];
  const float ea = eattr[e];
  const float* xlr = XL + (size_t)s * HC + h * CPH;
  const float* xrr = XR + (size_t)d * HC + h * CPH;
  const float* wer = We + h * CPH;
  const float* atr = att + h * CPH;
  float p = 0.f;
  #pragma unroll
  for (int j = 0; j < 5; ++j) {
    const int c = j * 64 + lane;
    float v = xlr[c] + xrr[c] + ea * wer[c];
    v = (v > 0.f) ? v : SLOPE * v;
    p += v * atr[c];
  }
  #pragma unroll
  for (int off = 32; off > 0; off >>= 1) p += __shfl_down(p, off, 64);
  if (lane == 0) score[e * HEADS + h] = p;
}

// ---------------- segment softmax stats: one thread per (node, head) ----------------
__global__ __launch_bounds__(256)
void node_stats(const float* __restrict__ score, const int* __restrict__ offs,
                const int* __restrict__ eids, float* __restrict__ nmax, float* __restrict__ nsum)
{
  const int i = blockIdx.x * 256 + threadIdx.x;
  if (i >= N_NODES * HEADS) return;
  const int n = i >> 3, h = i & 7;
  const int b = offs[n], e = offs[n + 1];
  float mx = -3e38f;
  for (int p = b; p < e; ++p) mx = fmaxf(mx, score[eids[p] * HEADS + h]);
  float sm = 0.f;
  for (int p = b; p < e; ++p) sm += __expf(score[eids[p] * HEADS + h] - mx);
  nmax[i] = mx;
  nsum[i] = sm;
}

// ---------------- alpha (in-place on score) ----------------
__global__ __launch_bounds__(256)
void compute_alpha(float* __restrict__ score, const int* __restrict__ dst,
                   const float* __restrict__ nmax, const float* __restrict__ nsum)
{
  const int i = blockIdx.x * 256 + threadIdx.x;
  if (i >= N_EDGES * HEADS) return;
  const int e = i >> 3, h = i & 7;
  const int d = dst[e];
  score[i] = __expf(score[i] - nmax[d * HEADS + h]) / nsum[d * HEADS + h];
}

// ---------------- aggregation: one block per node, 10 fp32 acc per thread ----------------
__global__ __launch_bounds__(256)
void aggregate(const float* __restrict__ XL, const float* __restrict__ alpha,
               const int* __restrict__ offs, const int* __restrict__ eids,
               const int* __restrict__ src, const float* __restrict__ bias,
               float* __restrict__ out)
{
  const int n = blockIdx.x;
  const int t = threadIdx.x;
  float acc[10];
  int hh[10];
  #pragma unroll
  for (int j = 0; j < 10; ++j) { acc[j] = 0.f; hh[j] = (j * 256 + t) / CPH; }
  const int b = offs[n], e = offs[n + 1];
  for (int p = b; p < e; ++p) {
    const int eid = eids[p];
    const float* row = XL + (size_t)src[eid] * HC;
    const float* al = alpha + eid * HEADS;
    #pragma unroll
    for (int j = 0; j < 10; ++j)
      acc[j] += al[hh[j]] * row[j * 256 + t];
  }
  #pragma unroll
  for (int j = 0; j < 10; ++j) {
    const int c = j * 256 + t;
    out[(size_t)n * HC + c] = acc[j] + bias[c];
  }
}

// ---------------- global mean pool (batch is sorted) ----------------
__global__ __launch_bounds__(256)
void pool_kernel(const float* __restrict__ Hm, const int* __restrict__ batch, float* __restrict__ out)
{
  __shared__ int se[2];
  const int g = blockIdx.x;
  const int chunk = blockIdx.y;
  const int t = threadIdx.x;
  if (t < 2) {
    const int target = g + t;
    int lo = 0, hi = N_NODES;
    while (lo < hi) { const int mid = (lo + hi) >> 1; if (batch[mid] < target) lo = mid + 1; else hi = mid; }
    se[t] = lo;
  }
  __syncthreads();
  const int s0 = se[0], s1 = se[1];
  const int c = chunk * 256 + t;
  float sum = 0.f;
  for (int n = s0; n < s1; ++n) sum += Hm[(size_t)n * HC + c];
  int cnt = s1 - s0; if (cnt < 1) cnt = 1;
  out[g * HC + c] = sum / (float)cnt;
}

// ---------------- host: one GATv2 layer (X f32 -> OUT f32) ----------------
static void run_layer(const float* X, const float* Wl, const float* bl,
                      const float* Wr, const float* br,
                      const float* We, const float* att, const float* bias,
                      const int* src, const int* dst, const float* eattr,
                      u16* Xh, u16* WT, float* XL, float* XR,
                      float* score, float* nmax, float* nsum,
                      const int* offs, const int* eids, float* OUT, hipStream_t stream)
{
  dim3 tgrid(HC / 64, F_IN / 64);
  dim3 ggrid((N_NODES + 127) / 128, HC / 128);
  cvt_f32_f16<<<(N_NODES * F_IN) / 1024, 256, 0, stream>>>(X, Xh, N_NODES * F_IN);
  transpose_w<<<tgrid, 256, 0, stream>>>(Wl, WT);
  gemm_bias<<<ggrid, 256, 0, stream>>>(Xh, WT, bl, XL, N_NODES, HC, F_IN);
  transpose_w<<<tgrid, 256, 0, stream>>>(Wr, WT);
  gemm_bias<<<ggrid, 256, 0, stream>>>(Xh, WT, br, XR, N_NODES, HC, F_IN);
  edge_scores<<<N_EDGES * HEADS / 4, 256, 0, stream>>>(XL, XR, We, att, eattr, src, dst, score);
  node_stats<<<(N_NODES * HEADS + 255) / 256, 256, 0, stream>>>(score, offs, eids, nmax, nsum);
  compute_alpha<<<(N_EDGES * HEADS + 255) / 256, 256, 0, stream>>>(score, dst, nmax, nsum);
  aggregate<<<N_NODES, 256, 0, stream>>>(XL, score, offs, eids, src, bias, OUT);
}

extern "C" void kernel_launch(void* const* d_in, const int* in_sizes, int n_in,
                              void* d_out, int out_size, void* d_ws, size_t ws_size,
                              hipStream_t stream)
{
  const float* x     = (const float*)d_in[0];
  const int*   eidx  = (const int*)d_in[1];
  const float* eattr = (const float*)d_in[2];
  const int*   batch = (const int*)d_in[3];
  const float* Wl1  = (const float*)d_in[4];
  const float* bl1  = (const float*)d_in[5];
  const float* Wr1  = (const float*)d_in[6];
  const float* br1  = (const float*)d_in[7];
  const float* We1  = (const float*)d_in[8];
  const float* att1 = (const float*)d_in[9];
  const float* bias1= (const float*)d_in[10];
  const float* Wl2  = (const float*)d_in[11];
  const float* bl2  = (const float*)d_in[12];
  const float* Wr2  = (const float*)d_in[13];
  const float* br2  = (const float*)d_in[14];
  const float* We2  = (const float*)d_in[15];
  const float* att2 = (const float*)d_in[16];
  const float* bias2= (const float*)d_in[17];
  float* out = (float*)d_out;

  const int* src = eidx;
  const int* dst = eidx + N_EDGES;

  char* w = (char*)d_ws;
  auto take = [&](size_t b) { char* p = w; w += (b + 255) & ~(size_t)255; return p; };
  u16*   Xh    = (u16*)take((size_t)N_NODES * F_IN * 2);
  u16*   WT    = (u16*)take((size_t)F_IN * HC * 2);
  float* XL    = (float*)take((size_t)N_NODES * HC * 4);
  float* XR    = (float*)take((size_t)N_NODES * HC * 4);
  float* H1    = (float*)take((size_t)N_NODES * HC * 4);
  float* score = (float*)take((size_t)N_EDGES * HEADS * 4);
  float* nmax  = (float*)take((size_t)N_NODES * HEADS * 4);
  float* nsum  = (float*)take((size_t)N_NODES * HEADS * 4);
  int*   counts= (int*)take((size_t)N_NODES * 4);
  int*   offs  = (int*)take((size_t)(N_NODES + 1) * 4);
  int*   cur   = (int*)take((size_t)N_NODES * 4);
  int*   eids  = (int*)take((size_t)N_EDGES * 4);

  hipMemsetAsync(counts, 0, N_NODES * 4, stream);
  count_edges<<<N_EDGES / 256, 256, 0, stream>>>(dst, counts);
  scan_offsets<<<1, 256, 0, stream>>>(counts, offs, cur);
  fill_csr<<<N_EDGES / 256, 256, 0, stream>>>(dst, cur, eids);

  // layer 1: x -> H1
  run_layer(x, Wl1, bl1, Wr1, br1, We1, att1, bias1, src, dst, eattr,
            Xh, WT, XL, XR, score, nmax, nsum, offs, eids, H1, stream);
  // layer 2: H1 -> H1 (aggregate reads XL/alpha only, so in-place output is safe)
  run_layer(H1, Wl2, bl2, Wr2, br2, We2, att2, bias2, src, dst, eattr,
            Xh, WT, XL, XR, score, nmax, nsum, offs, eids, H1, stream);

  pool_kernel<<<dim3(NGRAPH, HC / 256), 256, 0, stream>>>(H1, batch, out);
}

// Round 3
// 1485.894 us; speedup vs baseline: 1.2126x; 1.2126x over previous
//
#include <hip/hip_runtime.h>

typedef unsigned short u16;
typedef _Float16 f16;
typedef _Float16 f16x8 __attribute__((ext_vector_type(8)));
typedef float f32x4 __attribute__((ext_vector_type(4)));

#define AS1 __attribute__((address_space(1)))
#define AS3 __attribute__((address_space(3)))

constexpr int N_NODES = 8000;
constexpr int N_EDGES = 64000;
constexpr int F_IN    = 2560;   // in channels (== H*C, both layers)
constexpr int HEADS   = 8;
constexpr int CPH     = 320;    // channels per head
constexpr int HC      = 2560;   // HEADS*CPH
constexpr int NW      = 5120;   // fused GEMM output width (XL | XR)
constexpr int NGRAPH  = 16;
constexpr float SLOPE = 0.2f;

// ---------------- f32 -> f16 bulk convert (n divisible by 1024) ----------------
__global__ __launch_bounds__(256)
void cvt_f32_f16(const float* __restrict__ in, f16* __restrict__ out, int n)
{
  const int i = (blockIdx.x * 256 + threadIdx.x) * 4;
  if (i >= n) return;
  const float4 v = *(const float4*)(in + i);
  f16 o[4] = {(f16)v.x, (f16)v.y, (f16)v.z, (f16)v.w};
  *(ushort4*)(out + i) = *(const ushort4*)o;
}

// ------ weight transpose + convert: in f32 [R=2560][C=2560] -> out f16 [C][R] ------
__global__ __launch_bounds__(256)
void transpose_w(const float* __restrict__ in, f16* __restrict__ out)
{
  __shared__ u16 tile[64][66];     // +2 pad to break bank stride
  const int bx = blockIdx.x * 64;  // col tile (input)
  const int by = blockIdx.y * 64;  // row tile (input)
  const int tx = threadIdx.x & 63;
  const int ty = threadIdx.x >> 6;
  #pragma unroll
  for (int i = ty; i < 64; i += 4) {
    f16 h = (f16)in[(size_t)(by + i) * HC + bx + tx];
    u16 u; __builtin_memcpy(&u, &h, 2);
    tile[i][tx] = u;
  }
  __syncthreads();
  #pragma unroll
  for (int i = ty; i < 64; i += 4) {
    u16 u = tile[tx][i];
    f16 h; __builtin_memcpy(&h, &u, 2);
    out[(size_t)(bx + i) * F_IN + by + tx] = h;
  }
}

// ---- Fused GEMM: [XL|XR][M,5120](f16) = A[M,K](f16) @ BT[5120,K]^T + bias; fp32 acc ----
// m97 structure: 128x128 tile, BK=32, 4 waves (2x2), 16x16x32 f16 MFMA.
// Supergroup swizzle: 9 m-tiles x 40 n-tiles per group (63 = 7*9) for L2/L3 locality.
__global__ __launch_bounds__(256)
void gemm_fused(const f16* __restrict__ A, const f16* __restrict__ BT,
                const float* __restrict__ bl, const float* __restrict__ br,
                f16* __restrict__ XL, f16* __restrict__ XR, int M)
{
  __shared__ __align__(16) f16 sA[128 * 32];
  __shared__ __align__(16) f16 sB[128 * 32];
  const int t    = threadIdx.x;
  const int lane = t & 63;
  const int wave = t >> 6;
  // grid = (40, 63); swizzle into supergroups of 9 m-tiles x 40 n-tiles
  const int bid = blockIdx.y * 40 + blockIdx.x;
  const int sg  = bid / 360;
  const int rem = bid % 360;
  const int m0 = (sg * 9 + rem % 9) * 128;
  const int n0 = (rem / 9) * 128;
  const int fm = (wave >> 1) * 64;
  const int fn = (wave & 1) * 64;
  const int ml = lane & 15;
  const int kl = (lane >> 4) * 8;

  f32x4 acc[4][4] = {};

  for (int k0 = 0; k0 < F_IN; k0 += 32) {
    __syncthreads();
    #pragma unroll
    for (int jj = 0; jj < 2; ++jj) {
      const int flat = jj * 256 + t;
      const int r  = flat >> 2;
      const int kc = (flat & 3) << 3;
      int ra = m0 + r; ra = (ra < M) ? ra : (M - 1);
      const f16* ga = A + (size_t)ra * F_IN + k0 + kc;
      __builtin_amdgcn_global_load_lds((AS1 const void*)ga,
                                       (AS3 void*)(sA + flat * 8), 16, 0, 0);
      const f16* gb = BT + (size_t)(n0 + r) * F_IN + k0 + kc;
      __builtin_amdgcn_global_load_lds((AS1 const void*)gb,
                                       (AS3 void*)(sB + flat * 8), 16, 0, 0);
    }
    __syncthreads();

    f16x8 af[4], bfr[4];
    #pragma unroll
    for (int i = 0; i < 4; ++i)
      af[i] = *(const f16x8*)(sA + (fm + i * 16 + ml) * 32 + kl);
    #pragma unroll
    for (int j = 0; j < 4; ++j)
      bfr[j] = *(const f16x8*)(sB + (fn + j * 16 + ml) * 32 + kl);

    #pragma unroll
    for (int i = 0; i < 4; ++i)
      #pragma unroll
      for (int j = 0; j < 4; ++j)
        acc[i][j] = __builtin_amdgcn_mfma_f32_16x16x32_f16(af[i], bfr[j], acc[i][j], 0, 0, 0);
  }

  // epilogue: n0 block lies entirely in XL (gn<2560) or XR (2560 % 128 == 0)
  const bool left = (n0 < HC);
  f16* __restrict__ OUT = left ? XL : XR;
  const float* __restrict__ bias = left ? bl : br;
  const int nb = left ? n0 : (n0 - HC);
  const int rg = (lane >> 4) * 4;
  #pragma unroll
  for (int j = 0; j < 4; ++j) {
    const int gn = nb + fn + j * 16 + ml;
    const float bv = bias[gn];
    #pragma unroll
    for (int i = 0; i < 4; ++i) {
      #pragma unroll
      for (int r = 0; r < 4; ++r) {
        const int gm = m0 + fm + i * 16 + rg + r;
        if (gm < M) OUT[(size_t)gm * HC + gn] = (f16)(acc[i][j][r] + bv);
      }
    }
  }
}

// ---------------- CSR build ----------------
__global__ __launch_bounds__(256)
void count_edges(const int* __restrict__ dst, int* __restrict__ counts)
{
  const int e = blockIdx.x * 256 + threadIdx.x;
  if (e < N_EDGES) atomicAdd(&counts[dst[e]], 1);
}

__global__ __launch_bounds__(256)
void scan_offsets(const int* __restrict__ counts, int* __restrict__ offs, int* __restrict__ cur)
{
  __shared__ int wtot[4];
  const int t = threadIdx.x;
  const int lane = t & 63, wave = t >> 6;
  const int base = t * 32;
  int loc[32];
  int run = 0;
  #pragma unroll
  for (int i = 0; i < 32; ++i) {
    const int idx = base + i;
    const int v = (idx < N_NODES) ? counts[idx] : 0;
    loc[i] = run;
    run += v;
  }
  int incl = run;
  #pragma unroll
  for (int off = 1; off < 64; off <<= 1) {
    int y = __shfl_up(incl, off, 64);
    if (lane >= off) incl += y;
  }
  const int excl = incl - run;
  if (lane == 63) wtot[wave] = incl;
  __syncthreads();
  int wb = 0;
  for (int wv = 0; wv < wave; ++wv) wb += wtot[wv];
  const int mybase = wb + excl;
  #pragma unroll
  for (int i = 0; i < 32; ++i) {
    const int idx = base + i;
    if (idx < N_NODES) { offs[idx] = mybase + loc[i]; cur[idx] = mybase + loc[i]; }
  }
  if (t == 255) offs[N_NODES] = wb + incl;
}

__global__ __launch_bounds__(256)
void fill_csr(const int* __restrict__ dst, int* __restrict__ cur, int* __restrict__ eids)
{
  const int e = blockIdx.x * 256 + threadIdx.x;
  if (e < N_EDGES) {
    const int p = atomicAdd(&cur[dst[e]], 1);
    eids[p] = e;
  }
}

// ---------------- edge scores: one wave per (edge, head), f16 gathers ----------------
__global__ __launch_bounds__(256)
void edge_scores(const f16* __restrict__ XL, const f16* __restrict__ XR,
                 const float* __restrict__ We, const float* __restrict__ att,
                 const float* __restrict__ eattr,
                 const int* __restrict__ src, const int* __restrict__ dst,
                 float* __restrict__ score)
{
  const int W = (blockIdx.x * 256 + threadIdx.x) >> 6;
  const int lane = threadIdx.x & 63;
  if (W >= N_EDGES * HEADS) return;
  const int e = W >> 3, h = W & 7;
  const int s = src[e], d = dst[e];
  const float ea = eattr[e];
  const f16*   xlr = XL + (size_t)s * HC + h * CPH;
  const f16*   xrr = XR + (size_t)d * HC + h * CPH;
  const float* wer = We + h * CPH;
  const float* atr = att + h * CPH;
  float p = 0.f;
  #pragma unroll
  for (int j = 0; j < 5; ++j) {
    const int c = j * 64 + lane;
    float v = (float)xlr[c] + (float)xrr[c] + ea * wer[c];
    v = (v > 0.f) ? v : SLOPE * v;
    p += v * atr[c];
  }
  #pragma unroll
  for (int off = 32; off > 0; off >>= 1) p += __shfl_down(p, off, 64);
  if (lane == 0) score[e * HEADS + h] = p;
}

// ---------------- segment softmax stats: one thread per (node, head) ----------------
__global__ __launch_bounds__(256)
void node_stats(const float* __restrict__ score, const int* __restrict__ offs,
                const int* __restrict__ eids, float* __restrict__ nmax, float* __restrict__ nsum)
{
  const int i = blockIdx.x * 256 + threadIdx.x;
  if (i >= N_NODES * HEADS) return;
  const int n = i >> 3, h = i & 7;
  const int b = offs[n], e = offs[n + 1];
  float mx = -3e38f;
  for (int p = b; p < e; ++p) mx = fmaxf(mx, score[eids[p] * HEADS + h]);
  float sm = 0.f;
  for (int p = b; p < e; ++p) sm += __expf(score[eids[p] * HEADS + h] - mx);
  nmax[i] = mx;
  nsum[i] = sm;
}

// ---------------- alpha (in-place on score) ----------------
__global__ __launch_bounds__(256)
void compute_alpha(float* __restrict__ score, const int* __restrict__ dst,
                   const float* __restrict__ nmax, const float* __restrict__ nsum)
{
  const int i = blockIdx.x * 256 + threadIdx.x;
  if (i >= N_EDGES * HEADS) return;
  const int e = i >> 3, h = i & 7;
  const int d = dst[e];
  score[i] = __expf(score[i] - nmax[d * HEADS + h]) / nsum[d * HEADS + h];
}

// ------- aggregation: one block per node, 10 fp32 acc/thread, f16 gathers, f16 out -------
__global__ __launch_bounds__(256)
void aggregate(const f16* __restrict__ XL, const float* __restrict__ alpha,
               const int* __restrict__ offs, const int* __restrict__ eids,
               const int* __restrict__ src, const float* __restrict__ bias,
               f16* __restrict__ out)
{
  const int n = blockIdx.x;
  const int t = threadIdx.x;
  float acc[10];
  int hh[10];
  #pragma unroll
  for (int j = 0; j < 10; ++j) { acc[j] = 0.f; hh[j] = (j * 256 + t) / CPH; }
  const int b = offs[n], e = offs[n + 1];
  for (int p = b; p < e; ++p) {
    const int eid = eids[p];
    const f16* row = XL + (size_t)src[eid] * HC;
    const float* al = alpha + eid * HEADS;
    #pragma unroll
    for (int j = 0; j < 10; ++j)
      acc[j] += al[hh[j]] * (float)row[j * 256 + t];
  }
  #pragma unroll
  for (int j = 0; j < 10; ++j) {
    const int c = j * 256 + t;
    out[(size_t)n * HC + c] = (f16)(acc[j] + bias[c]);
  }
}

// ---------------- global mean pool (batch is sorted), f16 in, f32 out ----------------
__global__ __launch_bounds__(256)
void pool_kernel(const f16* __restrict__ Hm, const int* __restrict__ batch, float* __restrict__ out)
{
  __shared__ int se[2];
  const int g = blockIdx.x;
  const int chunk = blockIdx.y;
  const int t = threadIdx.x;
  if (t < 2) {
    const int target = g + t;
    int lo = 0, hi = N_NODES;
    while (lo < hi) { const int mid = (lo + hi) >> 1; if (batch[mid] < target) lo = mid + 1; else hi = mid; }
    se[t] = lo;
  }
  __syncthreads();
  const int s0 = se[0], s1 = se[1];
  const int c = chunk * 256 + t;
  float sum = 0.f;
  for (int n = s0; n < s1; ++n) sum += (float)Hm[(size_t)n * HC + c];
  int cnt = s1 - s0; if (cnt < 1) cnt = 1;
  out[g * HC + c] = sum / (float)cnt;
}

// ---------------- host: one GATv2 layer (A f16 -> OUT f16) ----------------
static void run_layer(const f16* A, const float* Wl, const float* bl,
                      const float* Wr, const float* br,
                      const float* We, const float* att, const float* bias,
                      const int* src, const int* dst, const float* eattr,
                      f16* WT, f16* XL, f16* XR,
                      float* score, float* nmax, float* nsum,
                      const int* offs, const int* eids, f16* OUT, hipStream_t stream)
{
  dim3 tgrid(HC / 64, F_IN / 64);
  dim3 ggrid(NW / 128, (N_NODES + 127) / 128);   // (40, 63), swizzled in-kernel
  transpose_w<<<tgrid, 256, 0, stream>>>(Wl, WT);
  transpose_w<<<tgrid, 256, 0, stream>>>(Wr, WT + (size_t)HC * F_IN);
  gemm_fused<<<ggrid, 256, 0, stream>>>(A, WT, bl, br, XL, XR, N_NODES);
  edge_scores<<<N_EDGES * HEADS / 4, 256, 0, stream>>>(XL, XR, We, att, eattr, src, dst, score);
  node_stats<<<(N_NODES * HEADS + 255) / 256, 256, 0, stream>>>(score, offs, eids, nmax, nsum);
  compute_alpha<<<(N_EDGES * HEADS + 255) / 256, 256, 0, stream>>>(score, dst, nmax, nsum);
  aggregate<<<N_NODES, 256, 0, stream>>>(XL, score, offs, eids, src, bias, OUT);
}

extern "C" void kernel_launch(void* const* d_in, const int* in_sizes, int n_in,
                              void* d_out, int out_size, void* d_ws, size_t ws_size,
                              hipStream_t stream)
{
  const float* x     = (const float*)d_in[0];
  const int*   eidx  = (const int*)d_in[1];
  const float* eattr = (const float*)d_in[2];
  const int*   batch = (const int*)d_in[3];
  const float* Wl1  = (const float*)d_in[4];
  const float* bl1  = (const float*)d_in[5];
  const float* Wr1  = (const float*)d_in[6];
  const float* br1  = (const float*)d_in[7];
  const float* We1  = (const float*)d_in[8];
  const float* att1 = (const float*)d_in[9];
  const float* bias1= (const float*)d_in[10];
  const float* Wl2  = (const float*)d_in[11];
  const float* bl2  = (const float*)d_in[12];
  const float* Wr2  = (const float*)d_in[13];
  const float* br2  = (const float*)d_in[14];
  const float* We2  = (const float*)d_in[15];
  const float* att2 = (const float*)d_in[16];
  const float* bias2= (const float*)d_in[17];
  float* out = (float*)d_out;

  const int* src = eidx;
  const int* dst = eidx + N_EDGES;

  char* w = (char*)d_ws;
  auto take = [&](size_t b) { char* p = w; w += (b + 255) & ~(size_t)255; return p; };
  f16*   Xh    = (f16*)take((size_t)N_NODES * F_IN * 2);   // layer-1 A / layer-1 out (reused)
  f16*   H2h   = (f16*)take((size_t)N_NODES * HC * 2);     // layer-2 out
  f16*   WT    = (f16*)take((size_t)NW * F_IN * 2);        // fused transposed weights
  f16*   XL    = (f16*)take((size_t)N_NODES * HC * 2);
  f16*   XR    = (f16*)take((size_t)N_NODES * HC * 2);
  float* score = (float*)take((size_t)N_EDGES * HEADS * 4);
  float* nmax  = (float*)take((size_t)N_NODES * HEADS * 4);
  float* nsum  = (float*)take((size_t)N_NODES * HEADS * 4);
  int*   counts= (int*)take((size_t)N_NODES * 4);
  int*   offs  = (int*)take((size_t)(N_NODES + 1) * 4);
  int*   cur   = (int*)take((size_t)N_NODES * 4);
  int*   eids  = (int*)take((size_t)N_EDGES * 4);

  hipMemsetAsync(counts, 0, N_NODES * 4, stream);
  count_edges<<<N_EDGES / 256, 256, 0, stream>>>(dst, counts);
  scan_offsets<<<1, 256, 0, stream>>>(counts, offs, cur);
  fill_csr<<<N_EDGES / 256, 256, 0, stream>>>(dst, cur, eids);

  cvt_f32_f16<<<(N_NODES * F_IN) / 1024, 256, 0, stream>>>(x, Xh, N_NODES * F_IN);

  // layer 1: Xh -> Xh (aggregate writes after GEMM reads; stream-ordered, safe)
  run_layer(Xh, Wl1, bl1, Wr1, br1, We1, att1, bias1, src, dst, eattr,
            WT, XL, XR, score, nmax, nsum, offs, eids, Xh, stream);
  // layer 2: Xh -> H2h
  run_layer(Xh, Wl2, bl2, Wr2, br2, We2, att2, bias2, src, dst, eattr,
            WT, XL, XR, score, nmax, nsum, offs, eids, H2h, stream);

  pool_kernel<<<dim3(NGRAPH, HC / 256), 256, 0, stream>>>(H2h, batch, out);
}

// Round 4
// 1253.165 us; speedup vs baseline: 1.4377x; 1.1857x over previous
//
#include <hip/hip_runtime.h>

typedef unsigned short u16;
typedef _Float16 f16;
typedef _Float16 f16x8 __attribute__((ext_vector_type(8)));
typedef float f32x4 __attribute__((ext_vector_type(4)));

#define AS1 __attribute__((address_space(1)))
#define AS3 __attribute__((address_space(3)))

constexpr int N_NODES = 8000;
constexpr int N_EDGES = 64000;
constexpr int F_IN    = 2560;   // in channels (== H*C, both layers)
constexpr int HEADS   = 8;
constexpr int CPH     = 320;    // channels per head
constexpr int HC      = 2560;   // HEADS*CPH
constexpr int NW      = 5120;   // fused GEMM output width (XL | XR)
constexpr int NGRAPH  = 16;
constexpr float SLOPE = 0.2f;

// ---------------- f32 -> f16 bulk convert (n divisible by 1024) ----------------
__global__ __launch_bounds__(256)
void cvt_f32_f16(const float* __restrict__ in, f16* __restrict__ out, int n)
{
  const int i = (blockIdx.x * 256 + threadIdx.x) * 4;
  if (i >= n) return;
  const float4 v = *(const float4*)(in + i);
  f16 o[4] = {(f16)v.x, (f16)v.y, (f16)v.z, (f16)v.w};
  *(ushort4*)(out + i) = *(const ushort4*)o;
}

// ------ weight transpose + convert: in f32 [R=2560][C=2560] -> out f16 [C][R] ------
__global__ __launch_bounds__(256)
void transpose_w(const float* __restrict__ in, f16* __restrict__ out)
{
  __shared__ u16 tile[64][66];     // +2 pad to break bank stride
  const int bx = blockIdx.x * 64;  // col tile (input)
  const int by = blockIdx.y * 64;  // row tile (input)
  const int tx = threadIdx.x & 63;
  const int ty = threadIdx.x >> 6;
  #pragma unroll
  for (int i = ty; i < 64; i += 4) {
    f16 h = (f16)in[(size_t)(by + i) * HC + bx + tx];
    u16 u; __builtin_memcpy(&u, &h, 2);
    tile[i][tx] = u;
  }
  __syncthreads();
  #pragma unroll
  for (int i = ty; i < 64; i += 4) {
    u16 u = tile[tx][i];
    f16 h; __builtin_memcpy(&h, &u, 2);
    out[(size_t)(bx + i) * F_IN + by + tx] = h;
  }
}

// ---- Fused GEMM: [XL|XR][M,5120](f16) = A[M,K](f16) @ BT[5120,K]^T + bias; fp32 acc ----
// m97 structure: 128x128 tile, BK=32, 4 waves (2x2), 16x16x32 f16 MFMA.
__global__ __launch_bounds__(256)
void gemm_fused(const f16* __restrict__ A, const f16* __restrict__ BT,
                const float* __restrict__ bl, const float* __restrict__ br,
                f16* __restrict__ XL, f16* __restrict__ XR, int M)
{
  __shared__ __align__(16) f16 sA[128 * 32];
  __shared__ __align__(16) f16 sB[128 * 32];
  const int t    = threadIdx.x;
  const int lane = t & 63;
  const int wave = t >> 6;
  // grid = (40, 63); swizzle into supergroups of 9 m-tiles x 40 n-tiles
  const int bid = blockIdx.y * 40 + blockIdx.x;
  const int sg  = bid / 360;
  const int rem = bid % 360;
  const int m0 = (sg * 9 + rem % 9) * 128;
  const int n0 = (rem / 9) * 128;
  const int fm = (wave >> 1) * 64;
  const int fn = (wave & 1) * 64;
  const int ml = lane & 15;
  const int kl = (lane >> 4) * 8;

  f32x4 acc[4][4] = {};

  for (int k0 = 0; k0 < F_IN; k0 += 32) {
    __syncthreads();
    #pragma unroll
    for (int jj = 0; jj < 2; ++jj) {
      const int flat = jj * 256 + t;
      const int r  = flat >> 2;
      const int kc = (flat & 3) << 3;
      int ra = m0 + r; ra = (ra < M) ? ra : (M - 1);
      const f16* ga = A + (size_t)ra * F_IN + k0 + kc;
      __builtin_amdgcn_global_load_lds((AS1 const void*)ga,
                                       (AS3 void*)(sA + flat * 8), 16, 0, 0);
      const f16* gb = BT + (size_t)(n0 + r) * F_IN + k0 + kc;
      __builtin_amdgcn_global_load_lds((AS1 const void*)gb,
                                       (AS3 void*)(sB + flat * 8), 16, 0, 0);
    }
    __syncthreads();

    f16x8 af[4], bfr[4];
    #pragma unroll
    for (int i = 0; i < 4; ++i)
      af[i] = *(const f16x8*)(sA + (fm + i * 16 + ml) * 32 + kl);
    #pragma unroll
    for (int j = 0; j < 4; ++j)
      bfr[j] = *(const f16x8*)(sB + (fn + j * 16 + ml) * 32 + kl);

    #pragma unroll
    for (int i = 0; i < 4; ++i)
      #pragma unroll
      for (int j = 0; j < 4; ++j)
        acc[i][j] = __builtin_amdgcn_mfma_f32_16x16x32_f16(af[i], bfr[j], acc[i][j], 0, 0, 0);
  }

  // epilogue: n0 block lies entirely in XL (gn<2560) or XR
  const bool left = (n0 < HC);
  f16* __restrict__ OUT = left ? XL : XR;
  const float* __restrict__ bias = left ? bl : br;
  const int nb = left ? n0 : (n0 - HC);
  const int rg = (lane >> 4) * 4;
  #pragma unroll
  for (int j = 0; j < 4; ++j) {
    const int gn = nb + fn + j * 16 + ml;
    const float bv = bias[gn];
    #pragma unroll
    for (int i = 0; i < 4; ++i) {
      #pragma unroll
      for (int r = 0; r < 4; ++r) {
        const int gm = m0 + fm + i * 16 + rg + r;
        if (gm < M) OUT[(size_t)gm * HC + gn] = (f16)(acc[i][j][r] + bv);
      }
    }
  }
}

// ---------------- CSR build ----------------
__global__ __launch_bounds__(256)
void count_edges(const int* __restrict__ dst, int* __restrict__ counts)
{
  const int e = blockIdx.x * 256 + threadIdx.x;
  if (e < N_EDGES) atomicAdd(&counts[dst[e]], 1);
}

__global__ __launch_bounds__(256)
void scan_offsets(const int* __restrict__ counts, int* __restrict__ offs, int* __restrict__ cur)
{
  __shared__ int wtot[4];
  const int t = threadIdx.x;
  const int lane = t & 63, wave = t >> 6;
  const int base = t * 32;
  int loc[32];
  int run = 0;
  #pragma unroll
  for (int i = 0; i < 32; ++i) {
    const int idx = base + i;
    const int v = (idx < N_NODES) ? counts[idx] : 0;
    loc[i] = run;
    run += v;
  }
  int incl = run;
  #pragma unroll
  for (int off = 1; off < 64; off <<= 1) {
    int y = __shfl_up(incl, off, 64);
    if (lane >= off) incl += y;
  }
  const int excl = incl - run;
  if (lane == 63) wtot[wave] = incl;
  __syncthreads();
  int wb = 0;
  for (int wv = 0; wv < wave; ++wv) wb += wtot[wv];
  const int mybase = wb + excl;
  #pragma unroll
  for (int i = 0; i < 32; ++i) {
    const int idx = base + i;
    if (idx < N_NODES) { offs[idx] = mybase + loc[i]; cur[idx] = mybase + loc[i]; }
  }
  if (t == 255) offs[N_NODES] = wb + incl;
}

__global__ __launch_bounds__(256)
void fill_csr(const int* __restrict__ dst, int* __restrict__ cur, int* __restrict__ eids)
{
  const int e = blockIdx.x * 256 + threadIdx.x;
  if (e < N_EDGES) {
    const int p = atomicAdd(&cur[dst[e]], 1);
    eids[p] = e;
  }
}

// ---- Fused edge phase: scores + online segment-softmax + aggregation, one pass ----
// One block per node; wave w handles heads 2w (lanes 0-31) and 2w+1 (lanes 32-63).
// Lane (l32) of head h owns channels c = h*320 + l32 + 32k, k=0..9.
// XL[src] rows are read ONCE; the same registers feed score and accumulation.
__global__ __launch_bounds__(256)
void gat_edge_fused(const f16* __restrict__ XL, const f16* __restrict__ XR,
                    const float* __restrict__ We, const float* __restrict__ att,
                    const float* __restrict__ eattr,
                    const int* __restrict__ src,
                    const int* __restrict__ offs, const int* __restrict__ eids,
                    const float* __restrict__ bias,
                    f16* __restrict__ out)
{
  const int n    = blockIdx.x;
  const int t    = threadIdx.x;
  const int wave = t >> 6;
  const int lane = t & 63;
  const int half = lane >> 5;
  const int l32  = lane & 31;
  const int h    = wave * 2 + half;
  const int cb   = h * CPH + l32;     // + 32*k

  float xr[10], wv[10], av[10];
  #pragma unroll
  for (int k = 0; k < 10; ++k) {
    const int c = cb + 32 * k;
    xr[k] = (float)XR[(size_t)n * HC + c];
    wv[k] = We[c];
    av[k] = att[c];
  }

  float m = -3.0e38f, l = 0.f;
  float acc[10];
  #pragma unroll
  for (int k = 0; k < 10; ++k) acc[k] = 0.f;

  const int b = offs[n], e = offs[n + 1];
  for (int p = b; p < e; ++p) {
    const int eid  = eids[p];
    const int s    = src[eid];
    const float ea = eattr[eid];
    const f16* row = XL + (size_t)s * HC;
    float xl[10];
    float partial = 0.f;
    #pragma unroll
    for (int k = 0; k < 10; ++k) {
      xl[k] = (float)row[cb + 32 * k];
      float v = xl[k] + xr[k] + ea * wv[k];
      v = (v > 0.f) ? v : SLOPE * v;
      partial += v * av[k];
    }
    // reduce across the 32-lane half (masks < 32 keep halves closed)
    #pragma unroll
    for (int msk = 16; msk >= 1; msk >>= 1)
      partial += __shfl_xor(partial, msk, 64);
    const float sc    = partial;
    const float mn    = fmaxf(m, sc);
    const float scale = __expf(m - mn);
    const float w     = __expf(sc - mn);
    l = l * scale + w;
    #pragma unroll
    for (int k = 0; k < 10; ++k) acc[k] = acc[k] * scale + w * xl[k];
    m = mn;
  }

  const float inv = (l > 0.f) ? 1.f / l : 0.f;   // deg-0 node -> out = bias (matches ref)
  #pragma unroll
  for (int k = 0; k < 10; ++k) {
    const int c = cb + 32 * k;
    out[(size_t)n * HC + c] = (f16)(acc[k] * inv + bias[c]);
  }
}

// ---------------- global mean pool (batch is sorted), f16 in, f32 out ----------------
__global__ __launch_bounds__(256)
void pool_kernel(const f16* __restrict__ Hm, const int* __restrict__ batch, float* __restrict__ out)
{
  __shared__ int se[2];
  const int g = blockIdx.x;
  const int chunk = blockIdx.y;
  const int t = threadIdx.x;
  if (t < 2) {
    const int target = g + t;
    int lo = 0, hi = N_NODES;
    while (lo < hi) { const int mid = (lo + hi) >> 1; if (batch[mid] < target) lo = mid + 1; else hi = mid; }
    se[t] = lo;
  }
  __syncthreads();
  const int s0 = se[0], s1 = se[1];
  const int c = chunk * 256 + t;
  float sum = 0.f;
  for (int n = s0; n < s1; ++n) sum += (float)Hm[(size_t)n * HC + c];
  int cnt = s1 - s0; if (cnt < 1) cnt = 1;
  out[g * HC + c] = sum / (float)cnt;
}

// ---------------- host: one GATv2 layer (A f16 -> OUT f16) ----------------
static void run_layer(const f16* A, const float* Wl, const float* bl,
                      const float* Wr, const float* br,
                      const float* We, const float* att, const float* bias,
                      const int* src, const float* eattr,
                      f16* WT, f16* XL, f16* XR,
                      const int* offs, const int* eids, f16* OUT, hipStream_t stream)
{
  dim3 tgrid(HC / 64, F_IN / 64);
  dim3 ggrid(NW / 128, (N_NODES + 127) / 128);   // (40, 63), swizzled in-kernel
  transpose_w<<<tgrid, 256, 0, stream>>>(Wl, WT);
  transpose_w<<<tgrid, 256, 0, stream>>>(Wr, WT + (size_t)HC * F_IN);
  gemm_fused<<<ggrid, 256, 0, stream>>>(A, WT, bl, br, XL, XR, N_NODES);
  gat_edge_fused<<<N_NODES, 256, 0, stream>>>(XL, XR, We, att, eattr, src, offs, eids, bias, OUT);
}

extern "C" void kernel_launch(void* const* d_in, const int* in_sizes, int n_in,
                              void* d_out, int out_size, void* d_ws, size_t ws_size,
                              hipStream_t stream)
{
  const float* x     = (const float*)d_in[0];
  const int*   eidx  = (const int*)d_in[1];
  const float* eattr = (const float*)d_in[2];
  const int*   batch = (const int*)d_in[3];
  const float* Wl1  = (const float*)d_in[4];
  const float* bl1  = (const float*)d_in[5];
  const float* Wr1  = (const float*)d_in[6];
  const float* br1  = (const float*)d_in[7];
  const float* We1  = (const float*)d_in[8];
  const float* att1 = (const float*)d_in[9];
  const float* bias1= (const float*)d_in[10];
  const float* Wl2  = (const float*)d_in[11];
  const float* bl2  = (const float*)d_in[12];
  const float* Wr2  = (const float*)d_in[13];
  const float* br2  = (const float*)d_in[14];
  const float* We2  = (const float*)d_in[15];
  const float* att2 = (const float*)d_in[16];
  const float* bias2= (const float*)d_in[17];
  float* out = (float*)d_out;

  const int* src = eidx;
  const int* dst = eidx + N_EDGES;

  char* w = (char*)d_ws;
  auto take = [&](size_t b) { char* p = w; w += (b + 255) & ~(size_t)255; return p; };
  f16*   Xh    = (f16*)take((size_t)N_NODES * F_IN * 2);   // layer-1 A / layer-1 out (reused)
  f16*   H2h   = (f16*)take((size_t)N_NODES * HC * 2);     // layer-2 out
  f16*   WT    = (f16*)take((size_t)NW * F_IN * 2);        // fused transposed weights
  f16*   XL    = (f16*)take((size_t)N_NODES * HC * 2);
  f16*   XR    = (f16*)take((size_t)N_NODES * HC * 2);
  int*   counts= (int*)take((size_t)N_NODES * 4);
  int*   offs  = (int*)take((size_t)(N_NODES + 1) * 4);
  int*   cur   = (int*)take((size_t)N_NODES * 4);
  int*   eids  = (int*)take((size_t)N_EDGES * 4);

  hipMemsetAsync(counts, 0, N_NODES * 4, stream);
  count_edges<<<N_EDGES / 256, 256, 0, stream>>>(dst, counts);
  scan_offsets<<<1, 256, 0, stream>>>(counts, offs, cur);
  fill_csr<<<N_EDGES / 256, 256, 0, stream>>>(dst, cur, eids);

  cvt_f32_f16<<<(N_NODES * F_IN) / 1024, 256, 0, stream>>>(x, Xh, N_NODES * F_IN);

  // layer 1: Xh -> Xh (edge kernel writes after GEMM has consumed Xh; stream-ordered, safe)
  run_layer(Xh, Wl1, bl1, Wr1, br1, We1, att1, bias1, src, eattr,
            WT, XL, XR, offs, eids, Xh, stream);
  // layer 2: Xh -> H2h
  run_layer(Xh, Wl2, bl2, Wr2, br2, We2, att2, bias2, src, eattr,
            WT, XL, XR, offs, eids, H2h, stream);

  pool_kernel<<<dim3(NGRAPH, HC / 256), 256, 0, stream>>>(H2h, batch, out);
}

// Round 5
// 1048.179 us; speedup vs baseline: 1.7189x; 1.1956x over previous
//
#include <hip/hip_runtime.h>

typedef unsigned short u16;
typedef _Float16 f16;
typedef _Float16 f16x8 __attribute__((ext_vector_type(8)));
typedef float f32x4 __attribute__((ext_vector_type(4)));

#define AS1 __attribute__((address_space(1)))
#define AS3 __attribute__((address_space(3)))

constexpr int N_NODES = 8000;
constexpr int N_EDGES = 64000;
constexpr int F_IN    = 2560;   // in channels (== H*C, both layers)
constexpr int HEADS   = 8;
constexpr int CPH     = 320;    // channels per head
constexpr int HC      = 2560;   // HEADS*CPH
constexpr int NW      = 5120;   // fused GEMM output width (XL | XR)
constexpr int NGRAPH  = 16;
constexpr float SLOPE = 0.2f;

// ---------------- f32 -> f16 bulk convert (n divisible by 1024) ----------------
__global__ __launch_bounds__(256)
void cvt_f32_f16(const float* __restrict__ in, f16* __restrict__ out, int n)
{
  const int i = (blockIdx.x * 256 + threadIdx.x) * 4;
  if (i >= n) return;
  const float4 v = *(const float4*)(in + i);
  f16 o[4] = {(f16)v.x, (f16)v.y, (f16)v.z, (f16)v.w};
  *(ushort4*)(out + i) = *(const ushort4*)o;
}

// ------ weight transpose + convert: in f32 [R=2560][C=2560] -> out f16 [C][R] ------
__global__ __launch_bounds__(256)
void transpose_w(const float* __restrict__ in, f16* __restrict__ out)
{
  __shared__ u16 tile[64][66];     // +2 pad to break bank stride
  const int bx = blockIdx.x * 64;  // col tile (input)
  const int by = blockIdx.y * 64;  // row tile (input)
  const int tx = threadIdx.x & 63;
  const int ty = threadIdx.x >> 6;
  #pragma unroll
  for (int i = ty; i < 64; i += 4) {
    f16 h = (f16)in[(size_t)(by + i) * HC + bx + tx];
    u16 u; __builtin_memcpy(&u, &h, 2);
    tile[i][tx] = u;
  }
  __syncthreads();
  #pragma unroll
  for (int i = ty; i < 64; i += 4) {
    u16 u = tile[tx][i];
    f16 h; __builtin_memcpy(&h, &u, 2);
    out[(size_t)(bx + i) * F_IN + by + tx] = h;
  }
}

// ---- Fused GEMM: [XL|XR][M,5120](f16) = A[M,K](f16) @ BT[5120,K]^T + bias; fp32 acc ----
// 256x128 tile, BK=32, 512 threads / 8 waves (4x2), each wave 64x64 (16 MFMA/K-step).
// LDS k-chunk XOR swizzle (phys = logical ^ ((row>>1)&3)) to spread ds_read_b128 banks.
__global__ __launch_bounds__(512)
void gemm_fused(const f16* __restrict__ A, const f16* __restrict__ BT,
                const float* __restrict__ bl, const float* __restrict__ br,
                f16* __restrict__ XL, f16* __restrict__ XR, int M)
{
  __shared__ __align__(16) f16 sA[256 * 32];   // 16 KB
  __shared__ __align__(16) f16 sB[128 * 32];   // 8 KB
  const int t    = threadIdx.x;     // 0..511
  const int lane = t & 63;
  const int wave = t >> 6;          // 0..7
  // m-fastest order: 32 consecutive blocks share one B-tile (L2-resident)
  const int m0 = (blockIdx.x & 31) * 256;
  const int n0 = (blockIdx.x >> 5) * 128;
  const int fm = (wave >> 1) * 64;  // 0..192
  const int fn = (wave & 1) * 64;   // 0,64
  const int ml = lane & 15;
  const int lq = lane >> 4;         // logical k-chunk 0..3

  f32x4 acc[4][4] = {};

  for (int k0 = 0; k0 < F_IN; k0 += 32) {
    __syncthreads();
    // stage A: 1024 chunk-slots (256 rows x 4 chunks of 8 f16), 2 per thread
    #pragma unroll
    for (int j = 0; j < 2; ++j) {
      const int s = j * 512 + t;
      const int r = s >> 2;
      const int lc = (s & 3) ^ ((r >> 1) & 3);   // logical chunk for this phys slot
      int ra = m0 + r; ra = (ra < M) ? ra : (M - 1);
      const f16* ga = A + (size_t)ra * F_IN + k0 + lc * 8;
      __builtin_amdgcn_global_load_lds((AS1 const void*)ga,
                                       (AS3 void*)(sA + s * 8), 16, 0, 0);
    }
    // stage B: 512 chunk-slots (128 rows x 4 chunks), 1 per thread
    {
      const int s = t;
      const int r = s >> 2;
      const int lc = (s & 3) ^ ((r >> 1) & 3);
      const f16* gb = BT + (size_t)(n0 + r) * F_IN + k0 + lc * 8;
      __builtin_amdgcn_global_load_lds((AS1 const void*)gb,
                                       (AS3 void*)(sB + s * 8), 16, 0, 0);
    }
    __syncthreads();

    f16x8 af[4], bfr[4];
    #pragma unroll
    for (int i = 0; i < 4; ++i) {
      const int row = fm + i * 16 + ml;
      const int p = lq ^ ((row >> 1) & 3);
      af[i] = *(const f16x8*)(sA + (row * 4 + p) * 8);
    }
    #pragma unroll
    for (int j = 0; j < 4; ++j) {
      const int row = fn + j * 16 + ml;
      const int p = lq ^ ((row >> 1) & 3);
      bfr[j] = *(const f16x8*)(sB + (row * 4 + p) * 8);
    }

    #pragma unroll
    for (int i = 0; i < 4; ++i)
      #pragma unroll
      for (int j = 0; j < 4; ++j)
        acc[i][j] = __builtin_amdgcn_mfma_f32_16x16x32_f16(af[i], bfr[j], acc[i][j], 0, 0, 0);
  }

  // epilogue: n0 block (128 wide) lies entirely in XL (n0<2560) or XR
  const bool left = (n0 < HC);
  f16* __restrict__ OUT = left ? XL : XR;
  const float* __restrict__ bias = left ? bl : br;
  const int nb = left ? n0 : (n0 - HC);
  const int rg = (lane >> 4) * 4;
  #pragma unroll
  for (int j = 0; j < 4; ++j) {
    const int gn = nb + fn + j * 16 + ml;
    const float bv = bias[gn];
    #pragma unroll
    for (int i = 0; i < 4; ++i) {
      #pragma unroll
      for (int r = 0; r < 4; ++r) {
        const int gm = m0 + fm + i * 16 + rg + r;
        if (gm < M) OUT[(size_t)gm * HC + gn] = (f16)(acc[i][j][r] + bv);
      }
    }
  }
}

// ---------------- CSR build ----------------
__global__ __launch_bounds__(256)
void count_edges(const int* __restrict__ dst, int* __restrict__ counts)
{
  const int e = blockIdx.x * 256 + threadIdx.x;
  if (e < N_EDGES) atomicAdd(&counts[dst[e]], 1);
}

__global__ __launch_bounds__(256)
void scan_offsets(const int* __restrict__ counts, int* __restrict__ offs, int* __restrict__ cur)
{
  __shared__ int wtot[4];
  const int t = threadIdx.x;
  const int lane = t & 63, wave = t >> 6;
  const int base = t * 32;
  int loc[32];
  int run = 0;
  #pragma unroll
  for (int i = 0; i < 32; ++i) {
    const int idx = base + i;
    const int v = (idx < N_NODES) ? counts[idx] : 0;
    loc[i] = run;
    run += v;
  }
  int incl = run;
  #pragma unroll
  for (int off = 1; off < 64; off <<= 1) {
    int y = __shfl_up(incl, off, 64);
    if (lane >= off) incl += y;
  }
  const int excl = incl - run;
  if (lane == 63) wtot[wave] = incl;
  __syncthreads();
  int wb = 0;
  for (int wv = 0; wv < wave; ++wv) wb += wtot[wv];
  const int mybase = wb + excl;
  #pragma unroll
  for (int i = 0; i < 32; ++i) {
    const int idx = base + i;
    if (idx < N_NODES) { offs[idx] = mybase + loc[i]; cur[idx] = mybase + loc[i]; }
  }
  if (t == 255) offs[N_NODES] = wb + incl;
}

__global__ __launch_bounds__(256)
void fill_csr(const int* __restrict__ dst, int* __restrict__ cur, int* __restrict__ eids)
{
  const int e = blockIdx.x * 256 + threadIdx.x;
  if (e < N_EDGES) {
    const int p = atomicAdd(&cur[dst[e]], 1);
    eids[p] = e;
  }
}

// ---- Fused edge phase: scores + online segment-softmax + aggregation, one pass ----
__global__ __launch_bounds__(256)
void gat_edge_fused(const f16* __restrict__ XL, const f16* __restrict__ XR,
                    const float* __restrict__ We, const float* __restrict__ att,
                    const float* __restrict__ eattr,
                    const int* __restrict__ src,
                    const int* __restrict__ offs, const int* __restrict__ eids,
                    const float* __restrict__ bias,
                    f16* __restrict__ out)
{
  const int n    = blockIdx.x;
  const int t    = threadIdx.x;
  const int wave = t >> 6;
  const int lane = t & 63;
  const int half = lane >> 5;
  const int l32  = lane & 31;
  const int h    = wave * 2 + half;
  const int cb   = h * CPH + l32;     // + 32*k

  float xr[10], wv[10], av[10];
  #pragma unroll
  for (int k = 0; k < 10; ++k) {
    const int c = cb + 32 * k;
    xr[k] = (float)XR[(size_t)n * HC + c];
    wv[k] = We[c];
    av[k] = att[c];
  }

  float m = -3.0e38f, l = 0.f;
  float acc[10];
  #pragma unroll
  for (int k = 0; k < 10; ++k) acc[k] = 0.f;

  const int b = offs[n], e = offs[n + 1];
  for (int p = b; p < e; ++p) {
    const int eid  = eids[p];
    const int s    = src[eid];
    const float ea = eattr[eid];
    const f16* row = XL + (size_t)s * HC;
    float xl[10];
    float partial = 0.f;
    #pragma unroll
    for (int k = 0; k < 10; ++k) {
      xl[k] = (float)row[cb + 32 * k];
      float v = xl[k] + xr[k] + ea * wv[k];
      v = (v > 0.f) ? v : SLOPE * v;
      partial += v * av[k];
    }
    #pragma unroll
    for (int msk = 16; msk >= 1; msk >>= 1)
      partial += __shfl_xor(partial, msk, 64);
    const float sc    = partial;
    const float mn    = fmaxf(m, sc);
    const float scale = __expf(m - mn);
    const float w     = __expf(sc - mn);
    l = l * scale + w;
    #pragma unroll
    for (int k = 0; k < 10; ++k) acc[k] = acc[k] * scale + w * xl[k];
    m = mn;
  }

  const float inv = (l > 0.f) ? 1.f / l : 0.f;   // deg-0 node -> out = bias (matches ref)
  #pragma unroll
  for (int k = 0; k < 10; ++k) {
    const int c = cb + 32 * k;
    out[(size_t)n * HC + c] = (f16)(acc[k] * inv + bias[c]);
  }
}

// ---------------- global mean pool (batch is sorted), f16 in, f32 out ----------------
__global__ __launch_bounds__(256)
void pool_kernel(const f16* __restrict__ Hm, const int* __restrict__ batch, float* __restrict__ out)
{
  __shared__ int se[2];
  const int g = blockIdx.x;
  const int chunk = blockIdx.y;
  const int t = threadIdx.x;
  if (t < 2) {
    const int target = g + t;
    int lo = 0, hi = N_NODES;
    while (lo < hi) { const int mid = (lo + hi) >> 1; if (batch[mid] < target) lo = mid + 1; else hi = mid; }
    se[t] = lo;
  }
  __syncthreads();
  const int s0 = se[0], s1 = se[1];
  const int c = chunk * 256 + t;
  float sum = 0.f;
  for (int n = s0; n < s1; ++n) sum += (float)Hm[(size_t)n * HC + c];
  int cnt = s1 - s0; if (cnt < 1) cnt = 1;
  out[g * HC + c] = sum / (float)cnt;
}

// ---------------- host: one GATv2 layer (A f16 -> OUT f16) ----------------
static void run_layer(const f16* A, const float* Wl, const float* bl,
                      const float* Wr, const float* br,
                      const float* We, const float* att, const float* bias,
                      const int* src, const float* eattr,
                      f16* WT, f16* XL, f16* XR,
                      const int* offs, const int* eids, f16* OUT, hipStream_t stream)
{
  dim3 tgrid(HC / 64, F_IN / 64);
  transpose_w<<<tgrid, 256, 0, stream>>>(Wl, WT);
  transpose_w<<<tgrid, 256, 0, stream>>>(Wr, WT + (size_t)HC * F_IN);
  gemm_fused<<<32 * (NW / 128), 512, 0, stream>>>(A, WT, bl, br, XL, XR, N_NODES);
  gat_edge_fused<<<N_NODES, 256, 0, stream>>>(XL, XR, We, att, eattr, src, offs, eids, bias, OUT);
}

extern "C" void kernel_launch(void* const* d_in, const int* in_sizes, int n_in,
                              void* d_out, int out_size, void* d_ws, size_t ws_size,
                              hipStream_t stream)
{
  const float* x     = (const float*)d_in[0];
  const int*   eidx  = (const int*)d_in[1];
  const float* eattr = (const float*)d_in[2];
  const int*   batch = (const int*)d_in[3];
  const float* Wl1  = (const float*)d_in[4];
  const float* bl1  = (const float*)d_in[5];
  const float* Wr1  = (const float*)d_in[6];
  const float* br1  = (const float*)d_in[7];
  const float* We1  = (const float*)d_in[8];
  const float* att1 = (const float*)d_in[9];
  const float* bias1= (const float*)d_in[10];
  const float* Wl2  = (const float*)d_in[11];
  const float* bl2  = (const float*)d_in[12];
  const float* Wr2  = (const float*)d_in[13];
  const float* br2  = (const float*)d_in[14];
  const float* We2  = (const float*)d_in[15];
  const float* att2 = (const float*)d_in[16];
  const float* bias2= (const float*)d_in[17];
  float* out = (float*)d_out;

  const int* src = eidx;
  const int* dst = eidx + N_EDGES;

  char* w = (char*)d_ws;
  auto take = [&](size_t b) { char* p = w; w += (b + 255) & ~(size_t)255; return p; };
  f16*   Xh    = (f16*)take((size_t)N_NODES * F_IN * 2);   // layer-1 A / layer-1 out (reused)
  f16*   H2h   = (f16*)take((size_t)N_NODES * HC * 2);     // layer-2 out
  f16*   WT    = (f16*)take((size_t)NW * F_IN * 2);        // fused transposed weights
  f16*   XL    = (f16*)take((size_t)N_NODES * HC * 2);
  f16*   XR    = (f16*)take((size_t)N_NODES * HC * 2);
  int*   counts= (int*)take((size_t)N_NODES * 4);
  int*   offs  = (int*)take((size_t)(N_NODES + 1) * 4);
  int*   cur   = (int*)take((size_t)N_NODES * 4);
  int*   eids  = (int*)take((size_t)N_EDGES * 4);

  hipMemsetAsync(counts, 0, N_NODES * 4, stream);
  count_edges<<<N_EDGES / 256, 256, 0, stream>>>(dst, counts);
  scan_offsets<<<1, 256, 0, stream>>>(counts, offs, cur);
  fill_csr<<<N_EDGES / 256, 256, 0, stream>>>(dst, cur, eids);

  cvt_f32_f16<<<(N_NODES * F_IN) / 1024, 256, 0, stream>>>(x, Xh, N_NODES * F_IN);

  // layer 1: Xh -> Xh (edge kernel writes after GEMM has consumed Xh; stream-ordered, safe)
  run_layer(Xh, Wl1, bl1, Wr1, br1, We1, att1, bias1, src, eattr,
            WT, XL, XR, offs, eids, Xh, stream);
  // layer 2: Xh -> H2h
  run_layer(Xh, Wl2, bl2, Wr2, br2, We2, att2, bias2, src, eattr,
            WT, XL, XR, offs, eids, H2h, stream);

  pool_kernel<<<dim3(NGRAPH, HC / 256), 256, 0, stream>>>(H2h, batch, out);
}